// Round 1
// baseline (12805.219 us; speedup 1.0000x reference)
//
#include <hip/hip_runtime.h>
#include <hip/hip_bf16.h>

// Sizes (fixed by the problem)
#define TT 500
#define BB 64
#define KSZ 128
#define VSZ 128
#define HH 512
#define EE 256
#define VOC 4096
#define LL 250

__device__ __forceinline__ float sigm(float x) { return 1.0f / (1.0f + expf(-x)); }

// ---------------------------------------------------------------------------
// init: xT0 (ctx part = values[t=0], h1 part = 0), xT1 = 0, h2T0/h2T1 = 0,
// c1T = 0, c2T = 0.  ws float layout:
//   xT0    @ 0        (640*64)
//   xT1    @ 40960
//   h2T0   @ 81920    (128*64)
//   h2T1   @ 90112
//   c1T    @ 98304    (512*64)
//   c2T    @ 131072   (128*64)
//   h2ctx  @ 139264   (16000*256)
// ---------------------------------------------------------------------------
__global__ __launch_bounds__(256) void k_init(const float* __restrict__ values,
                                              float* __restrict__ ws) {
    int i = blockIdx.x * 256 + threadIdx.x;  // grid covers [0,139264)
    if (i < 8192) {
        // ctxT[k][b] = values[(t=0)*B*VS + b*VS + k]
        int k = i >> 6, b = i & 63;
        ws[i] = values[b * VSZ + k];
    } else {
        ws[i] = 0.0f;
    }
}

// ---------------------------------------------------------------------------
// Shared fp32 GEMM: C[m][n] = sum_{k<256} A[m][k]*B[n][k] + bias1[n] (+bias2[n])
// BM=BN=64, BK=32, 256 threads, 4x4 per thread.
// Used for EmbW precompute (M=4096,N=2048) and output projection (M=16000,N=4096).
// ---------------------------------------------------------------------------
__global__ __launch_bounds__(256) void k_gemm_tn(
        const float* __restrict__ A, int lda,
        const float* __restrict__ B, int ldb,
        const float* __restrict__ bias1, const float* __restrict__ bias2,
        float* __restrict__ C, int ldc) {
    const int tid = threadIdx.x;
    const int m0 = blockIdx.y * 64, n0 = blockIdx.x * 64;
    const int tx = tid & 15, ty = tid >> 4;
    const int lm = tid >> 2, lk = (tid & 3) * 8;

    __shared__ float As[32][68];
    __shared__ float Bs[32][68];

    float c[4][4] = {{0.f}};

    for (int kb = 0; kb < 256; kb += 32) {
        const float* ap = A + (size_t)(m0 + lm) * lda + kb + lk;
        const float* bp = B + (size_t)(n0 + lm) * ldb + kb + lk;
        float4 a0 = *(const float4*)(ap);
        float4 a1 = *(const float4*)(ap + 4);
        float4 b0 = *(const float4*)(bp);
        float4 b1 = *(const float4*)(bp + 4);
        __syncthreads();
        As[lk + 0][lm] = a0.x; As[lk + 1][lm] = a0.y; As[lk + 2][lm] = a0.z; As[lk + 3][lm] = a0.w;
        As[lk + 4][lm] = a1.x; As[lk + 5][lm] = a1.y; As[lk + 6][lm] = a1.z; As[lk + 7][lm] = a1.w;
        Bs[lk + 0][lm] = b0.x; Bs[lk + 1][lm] = b0.y; Bs[lk + 2][lm] = b0.z; Bs[lk + 3][lm] = b0.w;
        Bs[lk + 4][lm] = b1.x; Bs[lk + 5][lm] = b1.y; Bs[lk + 6][lm] = b1.z; Bs[lk + 7][lm] = b1.w;
        __syncthreads();
#pragma unroll
        for (int kk = 0; kk < 32; ++kk) {
            const float4 a = *(const float4*)&As[kk][ty * 4];
            const float4 b = *(const float4*)&Bs[kk][tx * 4];
            c[0][0] += a.x * b.x; c[0][1] += a.x * b.y; c[0][2] += a.x * b.z; c[0][3] += a.x * b.w;
            c[1][0] += a.y * b.x; c[1][1] += a.y * b.y; c[1][2] += a.y * b.z; c[1][3] += a.y * b.w;
            c[2][0] += a.z * b.x; c[2][1] += a.z * b.y; c[2][2] += a.z * b.z; c[2][3] += a.z * b.w;
            c[3][0] += a.w * b.x; c[3][1] += a.w * b.y; c[3][2] += a.w * b.z; c[3][3] += a.w * b.w;
        }
    }

    const int n = n0 + tx * 4;
    float4 bb = *(const float4*)&bias1[n];
    if (bias2) {
        float4 b2 = *(const float4*)&bias2[n];
        bb.x += b2.x; bb.y += b2.y; bb.z += b2.z; bb.w += b2.w;
    }
#pragma unroll
    for (int i = 0; i < 4; ++i) {
        float4 r;
        r.x = c[i][0] + bb.x; r.y = c[i][1] + bb.y; r.z = c[i][2] + bb.z; r.w = c[i][3] + bb.w;
        *(float4*)&C[(size_t)(m0 + ty * 4 + i) * ldc + n] = r;
    }
}

// ---------------------------------------------------------------------------
// LSTM1: gates1[b][j] = EmbW[tok[b]][j] + sum ctx*w_ih1[j][256+k] + sum h1*w_hh1[j][k]
// grid 256 blocks (2 h-indices each), 256 threads: lane=b (64), q=tid>>6:
// hl = q&1, ks = q>>1 (k-split in 2). Pointwise -> c1T, h1 -> xnext.
// x is stored transposed: xT[k*64+b], k<128 ctx, k>=128 h1 (512).
// ---------------------------------------------------------------------------
#define FMA4(ACC, W, X0, X1, X2, X3) (ACC) += (W).x*(X0) + (W).y*(X1) + (W).z*(X2) + (W).w*(X3)

__global__ __launch_bounds__(256) void k_lstm1(
        const float* __restrict__ xT,       // current [ctx;h1] transposed (640*64)
        float* __restrict__ xnext,          // write h1 at (128+h)*64+b
        float* __restrict__ c1T,            // (512*64) in-place
        const float* __restrict__ EmbW,     // (4096,2048) biases folded
        const float* __restrict__ w_ih1,    // (2048,384)
        const float* __restrict__ w_hh1,    // (2048,512)
        const int* __restrict__ text, int l) {
    const int tid = threadIdx.x;
    const int b = tid & 63;
    const int q = __builtin_amdgcn_readfirstlane(tid >> 6);
    const int hl = q & 1, ks = q >> 1;
    const int h = blockIdx.x * 2 + hl;  // 0..511

    float acc0 = 0.f, acc1 = 0.f, acc2 = 0.f, acc3 = 0.f;
    const float* xp = xT + b;             // ctx part base (lane)
    const float* xh = xT + 128 * 64 + b;  // h1 part base
    const float* w1 = w_hh1 + h * 512;
    const int G2 = 512 * 512;

    if (ks == 0) {
        int tok = (l == 0) ? 0 : text[b * LL + (l - 1)];
        const float* er = EmbW + tok * 2048;
        acc0 = er[h]; acc1 = er[512 + h]; acc2 = er[1024 + h]; acc3 = er[1536 + h];
        const float* w0 = w_ih1 + h * 384 + 256;
        const int G = 512 * 384;
#pragma unroll 4
        for (int k = 0; k < 128; k += 4) {
            float x0 = xp[(k + 0) * 64], x1 = xp[(k + 1) * 64];
            float x2 = xp[(k + 2) * 64], x3 = xp[(k + 3) * 64];
            float4 w;
            w = *(const float4*)(w0 + k);         FMA4(acc0, w, x0, x1, x2, x3);
            w = *(const float4*)(w0 + G + k);     FMA4(acc1, w, x0, x1, x2, x3);
            w = *(const float4*)(w0 + 2 * G + k); FMA4(acc2, w, x0, x1, x2, x3);
            w = *(const float4*)(w0 + 3 * G + k); FMA4(acc3, w, x0, x1, x2, x3);
        }
#pragma unroll 4
        for (int k = 0; k < 192; k += 4) {
            float x0 = xh[(k + 0) * 64], x1 = xh[(k + 1) * 64];
            float x2 = xh[(k + 2) * 64], x3 = xh[(k + 3) * 64];
            float4 w;
            w = *(const float4*)(w1 + k);          FMA4(acc0, w, x0, x1, x2, x3);
            w = *(const float4*)(w1 + G2 + k);     FMA4(acc1, w, x0, x1, x2, x3);
            w = *(const float4*)(w1 + 2 * G2 + k); FMA4(acc2, w, x0, x1, x2, x3);
            w = *(const float4*)(w1 + 3 * G2 + k); FMA4(acc3, w, x0, x1, x2, x3);
        }
    } else {
#pragma unroll 4
        for (int k = 192; k < 512; k += 4) {
            float x0 = xh[(k + 0) * 64], x1 = xh[(k + 1) * 64];
            float x2 = xh[(k + 2) * 64], x3 = xh[(k + 3) * 64];
            float4 w;
            w = *(const float4*)(w1 + k);          FMA4(acc0, w, x0, x1, x2, x3);
            w = *(const float4*)(w1 + G2 + k);     FMA4(acc1, w, x0, x1, x2, x3);
            w = *(const float4*)(w1 + 2 * G2 + k); FMA4(acc2, w, x0, x1, x2, x3);
            w = *(const float4*)(w1 + 3 * G2 + k); FMA4(acc3, w, x0, x1, x2, x3);
        }
    }

    __shared__ float part[2][4][64];
    if (ks == 1) {
        part[hl][0][b] = acc0; part[hl][1][b] = acc1;
        part[hl][2][b] = acc2; part[hl][3][b] = acc3;
    }
    __syncthreads();
    if (ks == 0) {
        acc0 += part[hl][0][b]; acc1 += part[hl][1][b];
        acc2 += part[hl][2][b]; acc3 += part[hl][3][b];
        float iv = sigm(acc0), fv = sigm(acc1), gv = tanhf(acc2), ov = sigm(acc3);
        float cold = c1T[h * 64 + b];
        float cnew = fv * cold + iv * gv;
        c1T[h * 64 + b] = cnew;
        xnext[(128 + h) * 64 + b] = ov * tanhf(cnew);
    }
}

// ---------------------------------------------------------------------------
// LSTM2: gates2[b][j] (j = g*128+r) = sum_{k<512} h1[k]*w_ih2[j][k] + b_ih2[j]
//                                   + sum_{k<128} h2[k]*w_hh2[j][k] + b_hh2[j]
// grid 128 blocks (one r each), 256 threads = 64 b x 4 k-splits.
// h1 read from xnext (h1 of THIS step); h2 from h2cur. Writes h2next, c2T, h2ctx.
// ---------------------------------------------------------------------------
__global__ __launch_bounds__(256) void k_lstm2(
        const float* __restrict__ h1src,   // xnext: h1 at offset 128*64
        const float* __restrict__ h2T,     // current h2 (128*64)
        float* __restrict__ h2next,
        float* __restrict__ c2T,
        const float* __restrict__ w_ih2,   // (512,512)
        const float* __restrict__ b_ih2,
        const float* __restrict__ w_hh2,   // (512,128)
        const float* __restrict__ b_hh2,
        float* __restrict__ h2ctx, int l) {
    const int tid = threadIdx.x;
    const int b = tid & 63;
    const int ks = __builtin_amdgcn_readfirstlane(tid >> 6);  // 0..3
    const int r = blockIdx.x;  // 0..127

    float acc0, acc1, acc2, acc3;
    if (ks == 0) {
        acc0 = b_ih2[r] + b_hh2[r];
        acc1 = b_ih2[128 + r] + b_hh2[128 + r];
        acc2 = b_ih2[256 + r] + b_hh2[256 + r];
        acc3 = b_ih2[384 + r] + b_hh2[384 + r];
    } else {
        acc0 = acc1 = acc2 = acc3 = 0.f;
    }

    const float* xh = h1src + 128 * 64 + b;
    const float* wA = w_ih2 + r * 512;
    const int GA = 128 * 512;
    const int k0 = ks * 160;
    const int k1 = (k0 + 160 < 512) ? (k0 + 160) : 512;
#pragma unroll 4
    for (int k = k0; k < k1; k += 4) {
        float x0 = xh[(k + 0) * 64], x1 = xh[(k + 1) * 64];
        float x2 = xh[(k + 2) * 64], x3 = xh[(k + 3) * 64];
        float4 w;
        w = *(const float4*)(wA + k);          FMA4(acc0, w, x0, x1, x2, x3);
        w = *(const float4*)(wA + GA + k);     FMA4(acc1, w, x0, x1, x2, x3);
        w = *(const float4*)(wA + 2 * GA + k); FMA4(acc2, w, x0, x1, x2, x3);
        w = *(const float4*)(wA + 3 * GA + k); FMA4(acc3, w, x0, x1, x2, x3);
    }
    if (ks == 3) {
        const float* xh2 = h2T + b;
        const float* wB = w_hh2 + r * 128;
        const int GB = 128 * 128;
#pragma unroll 4
        for (int k = 0; k < 128; k += 4) {
            float x0 = xh2[(k + 0) * 64], x1 = xh2[(k + 1) * 64];
            float x2 = xh2[(k + 2) * 64], x3 = xh2[(k + 3) * 64];
            float4 w;
            w = *(const float4*)(wB + k);          FMA4(acc0, w, x0, x1, x2, x3);
            w = *(const float4*)(wB + GB + k);     FMA4(acc1, w, x0, x1, x2, x3);
            w = *(const float4*)(wB + 2 * GB + k); FMA4(acc2, w, x0, x1, x2, x3);
            w = *(const float4*)(wB + 3 * GB + k); FMA4(acc3, w, x0, x1, x2, x3);
        }
    }

    __shared__ float part[3][4][64];
    if (ks >= 1) {
        part[ks - 1][0][b] = acc0; part[ks - 1][1][b] = acc1;
        part[ks - 1][2][b] = acc2; part[ks - 1][3][b] = acc3;
    }
    __syncthreads();
    if (ks == 0) {
        acc0 += part[0][0][b] + part[1][0][b] + part[2][0][b];
        acc1 += part[0][1][b] + part[1][1][b] + part[2][1][b];
        acc2 += part[0][2][b] + part[1][2][b] + part[2][2][b];
        acc3 += part[0][3][b] + part[1][3][b] + part[2][3][b];
        float iv = sigm(acc0), fv = sigm(acc1), gv = tanhf(acc2), ov = sigm(acc3);
        float cold = c2T[r * 64 + b];
        float cnew = fv * cold + iv * gv;
        c2T[r * 64 + b] = cnew;
        float h2v = ov * tanhf(cnew);
        h2next[r * 64 + b] = h2v;
        h2ctx[(size_t)(b * LL + l) * 256 + r] = h2v;
    }
}

// ---------------------------------------------------------------------------
// Attention (faithful): energy[t]=key[t,b,:].h2 ; me = (t<len)?e:0 ;
// score = softmax(me over all 500) ; ctx = sum score*values[t,b,:].
// One block per b, 256 threads.
// ---------------------------------------------------------------------------
__global__ __launch_bounds__(256) void k_attn(
        const float* __restrict__ key,      // (T,B,KS)
        const float* __restrict__ values,   // (T,B,VS)
        const int* __restrict__ speech_len,
        const float* __restrict__ h2new,    // h2 of this step (128*64)
        float* __restrict__ xnext,          // write ctx at k*64+b, k<128
        float* __restrict__ h2ctx, int l) {
    const int b = blockIdx.x;
    const int tid = threadIdx.x;
    __shared__ float h2s[128];
    __shared__ float sc[TT];
    __shared__ float red[256];

    if (tid < 128) h2s[tid] = h2new[tid * 64 + b];
    __syncthreads();

    const int len = speech_len[b];
    float lmax = -1e30f;
    for (int t = tid; t < TT; t += 256) {
        const float* kr = key + (size_t)(t * BB + b) * KSZ;
        float e = 0.f;
#pragma unroll 8
        for (int k = 0; k < KSZ; k += 4) {
            float4 kv = *(const float4*)(kr + k);
            e += kv.x * h2s[k] + kv.y * h2s[k + 1] + kv.z * h2s[k + 2] + kv.w * h2s[k + 3];
        }
        float me = (t < len) ? e : 0.0f;
        sc[t] = me;
        lmax = fmaxf(lmax, me);
    }
    red[tid] = lmax;
    __syncthreads();
    for (int s = 128; s > 0; s >>= 1) {
        if (tid < s) red[tid] = fmaxf(red[tid], red[tid + s]);
        __syncthreads();
    }
    const float m = red[0];
    __syncthreads();

    float lsum = 0.f;
    for (int t = tid; t < TT; t += 256) {
        float p = expf(sc[t] - m);
        sc[t] = p;
        lsum += p;
    }
    red[tid] = lsum;
    __syncthreads();
    for (int s = 128; s > 0; s >>= 1) {
        if (tid < s) red[tid] += red[tid + s];
        __syncthreads();
    }
    const float inv = 1.0f / red[0];
    __syncthreads();

    // context: 128 v-lanes x 2 t-halves
    const int v = tid & 127, half = tid >> 7;
    float acc = 0.f;
    const int t0 = half * 250;
    for (int t = t0; t < t0 + 250; ++t) {
        acc += sc[t] * values[(size_t)(t * BB + b) * VSZ + v];
    }
    red[tid] = acc;
    __syncthreads();
    if (tid < 128) {
        float ctx = (red[tid] + red[tid + 128]) * inv;
        xnext[v * 64 + b] = ctx;
        h2ctx[(size_t)(b * LL + l) * 256 + 128 + v] = ctx;
    }
}

// ---------------------------------------------------------------------------
extern "C" void kernel_launch(void* const* d_in, const int* in_sizes, int n_in,
                              void* d_out, int out_size, void* d_ws, size_t ws_size,
                              hipStream_t stream) {
    const float* key        = (const float*)d_in[0];
    const float* values     = (const float*)d_in[1];
    const int*   speech_len = (const int*)d_in[2];
    const int*   text       = (const int*)d_in[3];
    const float* embedding  = (const float*)d_in[4];
    const float* w_ih1 = (const float*)d_in[5];
    const float* b_ih1 = (const float*)d_in[6];
    const float* w_hh1 = (const float*)d_in[7];
    const float* b_hh1 = (const float*)d_in[8];
    const float* w_ih2 = (const float*)d_in[9];
    const float* b_ih2 = (const float*)d_in[10];
    const float* w_hh2 = (const float*)d_in[11];
    const float* b_hh2 = (const float*)d_in[12];
    const float* w_out = (const float*)d_in[13];
    const float* b_out = (const float*)d_in[14];
    float* out = (float*)d_out;

    float* ws   = (float*)d_ws;
    float* xT0  = ws;
    float* xT1  = ws + 40960;
    float* h2T0 = ws + 81920;
    float* h2T1 = ws + 90112;
    float* c1T  = ws + 98304;
    float* c2T  = ws + 131072;
    float* h2ctx = ws + 139264;
    float* EmbW = out;  // 4096*2048 floats scratch at head of out; overwritten by final GEMM

    k_init<<<544, 256, 0, stream>>>(values, ws);
    // EmbW[v][j] = embedding[v] . w_ih1[j][:256] + b_ih1[j] + b_hh1[j]
    k_gemm_tn<<<dim3(32, 64), 256, 0, stream>>>(embedding, 256, w_ih1, 384,
                                                b_ih1, b_hh1, EmbW, 2048);

    for (int l = 0; l < LL; ++l) {
        float* xcur   = (l & 1) ? xT1 : xT0;
        float* xnext  = (l & 1) ? xT0 : xT1;
        float* h2cur  = (l & 1) ? h2T1 : h2T0;
        float* h2next = (l & 1) ? h2T0 : h2T1;
        k_lstm1<<<256, 256, 0, stream>>>(xcur, xnext, c1T, EmbW, w_ih1, w_hh1, text, l);
        k_lstm2<<<128, 256, 0, stream>>>(xnext, h2cur, h2next, c2T,
                                         w_ih2, b_ih2, w_hh2, b_hh2, h2ctx, l);
        k_attn<<<64, 256, 0, stream>>>(key, values, speech_len, h2next, xnext, h2ctx, l);
    }

    // out[b*250+l][v] = h2ctx[b*250+l] . w_out[v] + b_out[v]
    k_gemm_tn<<<dim3(64, 250), 256, 0, stream>>>(h2ctx, 256, w_out, 256,
                                                 b_out, nullptr, out, 4096);
}